// Round 7
// baseline (624.104 us; speedup 1.0000x reference)
//
#include <hip/hip_runtime.h>

// GAT, 2 layers, H=2 heads, D=C=128, concat=False (head mean), L2 normalize after each layer.
// Float tensors: fp32 OR bf16 (runtime-probed). edge_index: int32 OR int64 (runtime-probed).
// Internal h-matrix bf16, stored XCD-SLICED: 8 slices x [N x 64B]; slice s holds output
// channels [16s,16s+16) of both heads (32B head0 + 32B head1). Slice -> blockIdx%8 -> XCD L2.

using short8  = __attribute__((ext_vector_type(8))) short;
using float4v = __attribute__((ext_vector_type(4))) float;

static __device__ __forceinline__ float bf2f(unsigned int u16) {
    union { unsigned int i; float f; } v; v.i = u16 << 16; return v.f;
}
static __device__ __forceinline__ float bflo(unsigned int p){
    union { unsigned int i; float f; } v; v.i = p << 16; return v.f;
}
static __device__ __forceinline__ float bfhi(unsigned int p){
    union { unsigned int i; float f; } v; v.i = p & 0xffff0000u; return v.f;
}
static __device__ __forceinline__ unsigned short f2bf(float f) {
    union { float f; unsigned int i; } v; v.f = f;
    unsigned int x = v.i;
    x += 0x7fffu + ((x >> 16) & 1u);   // RNE
    return (unsigned short)(x >> 16);
}
static __device__ __forceinline__ float leaky(float x){ return x > 0.f ? x : 0.2f * x; }

// ---------------- probe dtypes + zero cursor (fused) ----------------
__global__ __launch_bounds__(256) void k_probe_zero(const unsigned int* __restrict__ xw,
                                                    const int* __restrict__ ei,
                                                    int* __restrict__ flags,
                                                    int* __restrict__ cursor, int N) {
    int i = blockIdx.x * 256 + threadIdx.x;
    if (i < N) cursor[i] = 0;
    if (blockIdx.x == 0) {
        __shared__ int insane, oddnz;
        int t = threadIdx.x;
        if (t == 0) { insane = 0; oddnz = 0; }
        __syncthreads();
        unsigned int w = xw[t];
        if (((w >> 7) & 0xFFu) >= 154u) atomicOr(&insane, 1);
        if (ei[2 * t + 1] != 0) atomicOr(&oddnz, 1);
        __syncthreads();
        if (t == 0) { flags[0] = insane ? 1 : 0; flags[1] = oddnz ? 0 : 1; }
    }
}

// ---------------- W -> WT (bf16): WT[l][n][k] = W[l][k][n] ----------------
__global__ __launch_bounds__(256) void k_transpose(const void* __restrict__ W,
                                                   unsigned short* __restrict__ WT,
                                                   const int* __restrict__ flags) {
    int fx = flags[0];
    int idx = blockIdx.x * 256 + threadIdx.x;
    int layer = idx >> 15;
    int rem = idx & 32767;
    int k = rem >> 8, n = rem & 255;
    int srci = layer * 32768 + k * 256 + n;
    unsigned short v;
    if (fx) v = f2bf(((const float*)W)[srci]);
    else    v = ((const unsigned short*)W)[srci];
    WT[layer * 32768 + n * 128 + k] = v;
}

// ---------------- fused GEMM + alpha; Hb written in XCD-sliced layout ----------------
// one block per 16-row tile; wave w computes col tiles [4w,4w+4) (one head per wave).
// store: col=nt*16+r16 -> slice=(nt&7), pos=(nt>>3)*16+r16: Hb[(slice*N+row)*32+pos]
__global__ __launch_bounds__(256) void k_gemm_alpha(const void* __restrict__ X,
                                                    const unsigned short* __restrict__ WT,
                                                    const void* __restrict__ atts,
                                                    const void* __restrict__ attd,
                                                    int layer,
                                                    unsigned short* __restrict__ Hb,
                                                    float* __restrict__ as_, float* __restrict__ ad_,
                                                    int N, const int* __restrict__ flags) {
    __shared__ float lds_s[4][16], lds_d[4][16];
    int fx = flags[0];
    int mt = blockIdx.x;
    int wave = threadIdx.x >> 6;
    int lane = threadIdx.x & 63;
    int r16 = lane & 15, quad = lane >> 4;
    int m0 = mt << 4;
    int arow = m0 + r16; if (arow >= N) arow = N - 1;
    short8 a[4];
    if (fx) {
        const float* Xf = (const float*)X;
#pragma unroll
        for (int kk = 0; kk < 4; kk++) {
            const float4v* pv = (const float4v*)(Xf + (size_t)arow * 128 + kk * 32 + quad * 8);
            float4v lo = pv[0], hi = pv[1];
            short8 t;
            t[0] = (short)f2bf(lo[0]); t[1] = (short)f2bf(lo[1]);
            t[2] = (short)f2bf(lo[2]); t[3] = (short)f2bf(lo[3]);
            t[4] = (short)f2bf(hi[0]); t[5] = (short)f2bf(hi[1]);
            t[6] = (short)f2bf(hi[2]); t[7] = (short)f2bf(hi[3]);
            a[kk] = t;
        }
    } else {
        const unsigned short* Xh = (const unsigned short*)X;
#pragma unroll
        for (int kk = 0; kk < 4; kk++)
            a[kk] = *(const short8*)(Xh + (size_t)arow * 128 + kk * 32 + quad * 8);
    }
    int head = wave >> 1;
    float ps[4] = {0.f, 0.f, 0.f, 0.f}, pd[4] = {0.f, 0.f, 0.f, 0.f};
#pragma unroll
    for (int nn = 0; nn < 4; nn++) {
        int nt = wave * 4 + nn;
        float4v acc = {0.f, 0.f, 0.f, 0.f};
#pragma unroll
        for (int kk = 0; kk < 4; kk++) {
            short8 b = *(const short8*)(WT + (nt * 16 + r16) * 128 + kk * 32 + quad * 8);
            acc = __builtin_amdgcn_mfma_f32_16x16x32_bf16(a[kk], b, acc, 0, 0, 0);
        }
        int col = nt * 16 + r16;
        int c = col & 127;
        float sa, da;
        if (fx) {
            sa = ((const float*)atts)[layer * 256 + head * 128 + c];
            da = ((const float*)attd)[layer * 256 + head * 128 + c];
        } else {
            sa = bf2f(((const unsigned short*)atts)[layer * 256 + head * 128 + c]);
            da = bf2f(((const unsigned short*)attd)[layer * 256 + head * 128 + c]);
        }
        size_t sbase = (size_t)(nt & 7) * N * 32 + (nt >> 3) * 16 + r16;
#pragma unroll
        for (int r = 0; r < 4; r++) {
            int row = m0 + quad * 4 + r;           // C/D: col=lane&15, row=quad*4+reg  [m89]
            if (row < N) Hb[sbase + (size_t)row * 32] = f2bf(acc[r]);
            ps[r] += acc[r] * sa;
            pd[r] += acc[r] * da;
        }
    }
#pragma unroll
    for (int m = 1; m < 16; m <<= 1) {
#pragma unroll
        for (int r = 0; r < 4; r++) {
            ps[r] += __shfl_xor(ps[r], m);
            pd[r] += __shfl_xor(pd[r], m);
        }
    }
    if (r16 == 0) {
#pragma unroll
        for (int r = 0; r < 4; r++) {
            lds_s[wave][quad * 4 + r] = ps[r];
            lds_d[wave][quad * 4 + r] = pd[r];
        }
    }
    __syncthreads();
    if (threadIdx.x < 16) {
        int row = m0 + threadIdx.x;
        if (row < N) {
            float2 sv = { lds_s[0][threadIdx.x] + lds_s[1][threadIdx.x],
                          lds_s[2][threadIdx.x] + lds_s[3][threadIdx.x] };
            float2 dv = { lds_d[0][threadIdx.x] + lds_d[1][threadIdx.x],
                          lds_d[2][threadIdx.x] + lds_d[3][threadIdx.x] };
            *(float2*)(as_ + 2 * row) = sv;   // [head0, head1]
            *(float2*)(ad_ + 2 * row) = dv;
        }
    }
}

// ---------------- CSR build ----------------
static __device__ __forceinline__ int edge_dst(const int* ei, int E, int i, int is64) {
    return is64 ? ei[2 * E + 2 * i] : ei[E + i];
}
static __device__ __forceinline__ int edge_src(const int* ei, int E, int i, int is64) {
    return is64 ? ei[2 * i] : ei[i];
}

__global__ __launch_bounds__(256) void k_count(const int* __restrict__ ei, int E, int N,
                                               const int* __restrict__ flags, int* deg) {
    int i = blockIdx.x * 256 + threadIdx.x;
    if (i >= E + N) return;
    int dst;
    if (i < E) { dst = edge_dst(ei, E, i, flags[1]); if ((unsigned)dst >= (unsigned)N) dst = 0; }
    else dst = i - E;
    atomicAdd(&deg[dst], 1);
}

__global__ __launch_bounds__(1024) void k_scan1(const int* __restrict__ deg, int* __restrict__ excl,
                                                int* __restrict__ bsum, int n) {
    __shared__ int buf[1024];
    int t = threadIdx.x;
    int i = blockIdx.x * 1024 + t;
    int v = (i < n) ? deg[i] : 0;
    int x = v; buf[t] = v; __syncthreads();
    for (int off = 1; off < 1024; off <<= 1) {
        int add = (t >= off) ? buf[t - off] : 0;
        __syncthreads();
        x += add; buf[t] = x;
        __syncthreads();
    }
    if (i < n) excl[i] = x - v;
    if (t == 1023) bsum[blockIdx.x] = x;
}

__global__ __launch_bounds__(256) void k_scan2(int* bsum, int nb) {
    __shared__ int buf[256];
    int t = threadIdx.x;
    int v = (t < nb) ? bsum[t] : 0;
    int x = v; buf[t] = v; __syncthreads();
    for (int off = 1; off < 256; off <<= 1) {
        int add = (t >= off) ? buf[t - off] : 0;
        __syncthreads();
        x += add; buf[t] = x;
        __syncthreads();
    }
    if (t < nb) bsum[t] = x - v;
    if (t == nb - 1) bsum[nb] = x;
}

__global__ __launch_bounds__(256) void k_scan3(int* __restrict__ rowptr, const int* __restrict__ bsum,
                                               int* __restrict__ cursor, int N) {
    int i = blockIdx.x * 256 + threadIdx.x;
    if (i < N) {
        int r = rowptr[i] + bsum[i >> 10];
        rowptr[i] = r;
        cursor[i] = r;
    } else if (i == N) {
        rowptr[N] = bsum[(N + 1023) >> 10];
    }
}

__global__ __launch_bounds__(256) void k_scatter(const int* __restrict__ ei, int E, int N,
                                                 const int* __restrict__ flags,
                                                 int* __restrict__ cursor, int* __restrict__ csr) {
    int i = blockIdx.x * 256 + threadIdx.x;
    if (i >= E + N) return;
    int src, dst;
    if (i < E) {
        int is64 = flags[1];
        src = edge_src(ei, E, i, is64);
        dst = edge_dst(ei, E, i, is64);
        if ((unsigned)src >= (unsigned)N) src = 0;
        if ((unsigned)dst >= (unsigned)N) dst = 0;
    } else src = dst = i - E;
    int pos = atomicAdd(&cursor[dst], 1);
    csr[pos] = src;
}

// ---------------- per-node softmax -> NORMALIZED edge weights (float2 per edge) ----------------
__global__ __launch_bounds__(256) void k_weights(const float* __restrict__ as_, const float* __restrict__ ad_,
                                                 const int* __restrict__ rowptr, const int* __restrict__ csr,
                                                 float* __restrict__ wbuf, int N, int EL) {
    int n = blockIdx.x * 4 + (threadIdx.x >> 6);
    if (n >= N) return;
    int lane = threadIdx.x & 63;
    int start = rowptr[n], end = rowptr[n + 1];
    if (start < 0) start = 0;
    if (end > EL) end = EL;
    if (end < start) end = start;
    float2 adv = *(const float2*)(ad_ + 2 * n);
    float ad0 = adv.x, ad1 = adv.y;
    int deg = end - start;

    if (deg <= 64) {
        int e = start + lane;
        bool act = e < end;
        int s = 0; float l0 = -1e30f, l1 = -1e30f;
        if (act) {
            s = csr[e]; if ((unsigned)s >= (unsigned)N) s = 0;
            float2 av = *(const float2*)(as_ + 2 * s);
            l0 = leaky(av.x + ad0); l1 = leaky(av.y + ad1);
        }
        float m0 = l0, m1 = l1;
#pragma unroll
        for (int m = 1; m < 64; m <<= 1) { m0 = fmaxf(m0, __shfl_xor(m0, m)); m1 = fmaxf(m1, __shfl_xor(m1, m)); }
        float w0 = act ? __expf(l0 - m0) : 0.f;
        float w1 = act ? __expf(l1 - m1) : 0.f;
        float z0 = w0, z1 = w1;
#pragma unroll
        for (int m = 1; m < 64; m <<= 1) { z0 += __shfl_xor(z0, m); z1 += __shfl_xor(z1, m); }
        float inv0 = 1.f / (z0 + 1e-16f), inv1 = 1.f / (z1 + 1e-16f);
        if (act) { float2 o = { w0 * inv0, w1 * inv1 }; *(float2*)(wbuf + 2 * e) = o; }
    } else {
        float m0 = -1e30f, m1 = -1e30f;
        for (int i = start + lane; i < end; i += 64) {
            int s = csr[i]; if ((unsigned)s >= (unsigned)N) s = 0;
            float2 av = *(const float2*)(as_ + 2 * s);
            m0 = fmaxf(m0, leaky(av.x + ad0));
            m1 = fmaxf(m1, leaky(av.y + ad1));
        }
#pragma unroll
        for (int m = 1; m < 64; m <<= 1) { m0 = fmaxf(m0, __shfl_xor(m0, m)); m1 = fmaxf(m1, __shfl_xor(m1, m)); }
        float z0 = 0.f, z1 = 0.f;
        for (int i = start + lane; i < end; i += 64) {
            int s = csr[i]; if ((unsigned)s >= (unsigned)N) s = 0;
            float2 av = *(const float2*)(as_ + 2 * s);
            z0 += __expf(leaky(av.x + ad0) - m0);
            z1 += __expf(leaky(av.y + ad1) - m1);
        }
#pragma unroll
        for (int m = 1; m < 64; m <<= 1) { z0 += __shfl_xor(z0, m); z1 += __shfl_xor(z1, m); }
        float inv0 = 1.f / (z0 + 1e-16f), inv1 = 1.f / (z1 + 1e-16f);
        for (int i = start + lane; i < end; i += 64) {
            int s = csr[i]; if ((unsigned)s >= (unsigned)N) s = 0;
            float2 av = *(const float2*)(as_ + 2 * s);
            float2 o = { __expf(leaky(av.x + ad0) - m0) * inv0,
                         __expf(leaky(av.y + ad1) - m1) * inv1 };
            *(float2*)(wbuf + 2 * i) = o;
        }
    }
}

// ---------------- sliced weighted gather: out[n][16s..16s+16) pre-norm ----------------
// slice = blockIdx&7 (-> XCD via round-robin dispatch); wave per node; 8 groups x 8 lanes,
// group g handles edge t+g; lane sub=lane&7: sub<4 -> head0 chans 4sub.., sub>=4 -> head1.
__global__ __launch_bounds__(256) void k_gather(const unsigned short* __restrict__ Hb,
                                                const float* __restrict__ wbuf,
                                                const int* __restrict__ rowptr, const int* __restrict__ csr,
                                                const void* __restrict__ bias, int layer,
                                                const int* __restrict__ flags,
                                                void* __restrict__ outp, int N, int EL) {
    int fx = flags[0];
    int slice = blockIdx.x & 7;
    int n = (blockIdx.x >> 3) * 4 + (threadIdx.x >> 6);
    if (n >= N) return;
    int lane = threadIdx.x & 63;
    int g = lane >> 3;
    int sub = lane & 7;
    int hsel = (lane >> 2) & 1;   // head for this lane's 4 channels
    int start = rowptr[n], end = rowptr[n + 1];
    if (start < 0) start = 0;
    if (end > EL) end = EL;
    if (end < start) end = start;

    const unsigned short* base = Hb + (size_t)slice * N * 32 + sub * 4;
    float a0 = 0.f, a1 = 0.f, a2 = 0.f, a3 = 0.f;
    for (int t = start; t < end; t += 8) {
        int e = t + g;
        if (e < end) {
            int s = csr[e]; if ((unsigned)s >= (unsigned)N) s = 0;
            float w = wbuf[2 * e + hsel];
            uint2 q = *(const uint2*)(base + (size_t)s * 32);
            a0 += w * bflo(q.x); a1 += w * bfhi(q.x);
            a2 += w * bflo(q.y); a3 += w * bfhi(q.y);
        }
    }
    // sum the 8 edge-groups (lanes differing in bits 3..5)
#pragma unroll
    for (int m = 8; m < 64; m <<= 1) {
        a0 += __shfl_xor(a0, m); a1 += __shfl_xor(a1, m);
        a2 += __shfl_xor(a2, m); a3 += __shfl_xor(a3, m);
    }
    // head mean (partner lane sub^4 holds other head, same channels)
    float v0 = 0.5f * (a0 + __shfl_xor(a0, 4));
    float v1 = 0.5f * (a1 + __shfl_xor(a1, 4));
    float v2 = 0.5f * (a2 + __shfl_xor(a2, 4));
    float v3 = 0.5f * (a3 + __shfl_xor(a3, 4));

    if (lane < 4) {                       // g==0, sub==lane: channels slice*16 + lane*4 ..
        int c = slice * 16 + lane * 4;
        float b0, b1, b2, b3;
        if (fx) {
            const float* bf = (const float*)bias + layer * 128 + c;
            b0 = bf[0]; b1 = bf[1]; b2 = bf[2]; b3 = bf[3];
        } else {
            uint2 bv = *(const uint2*)((const unsigned short*)bias + layer * 128 + c);
            b0 = bflo(bv.x); b1 = bfhi(bv.x); b2 = bflo(bv.y); b3 = bfhi(bv.y);
        }
        v0 += b0; v1 += b1; v2 += b2; v3 += b3;
        if (fx) {
            float4 o = { v0, v1, v2, v3 };
            *(float4*)((float*)outp + (size_t)n * 128 + c) = o;
        } else {
            uint2 pk;
            pk.x = (unsigned int)f2bf(v0) | ((unsigned int)f2bf(v1) << 16);
            pk.y = (unsigned int)f2bf(v2) | ((unsigned int)f2bf(v3) << 16);
            *(uint2*)((unsigned short*)outp + (size_t)n * 128 + c) = pk;
        }
    }
}

// ---------------- in-place row L2 normalize of out ----------------
__global__ __launch_bounds__(256) void k_norm(void* __restrict__ outp,
                                              const int* __restrict__ flags, int N) {
    int fx = flags[0];
    int n = blockIdx.x * 4 + (threadIdx.x >> 6);
    if (n >= N) return;
    int lane = threadIdx.x & 63;
    float a, b;
    if (fx) {
        float2 v = *(float2*)((float*)outp + (size_t)n * 128 + lane * 2);
        a = v.x; b = v.y;
    } else {
        unsigned int p = *(unsigned int*)((unsigned short*)outp + (size_t)n * 128 + lane * 2);
        a = bflo(p); b = bfhi(p);
    }
    float ss = a * a + b * b;
#pragma unroll
    for (int m = 1; m < 64; m <<= 1) ss += __shfl_xor(ss, m);
    float inv = 1.f / fmaxf(sqrtf(ss), 1e-12f);
    if (fx) {
        float2 o = { a * inv, b * inv };
        *(float2*)((float*)outp + (size_t)n * 128 + lane * 2) = o;
    } else {
        unsigned int pk = (unsigned int)f2bf(a * inv) | ((unsigned int)f2bf(b * inv) << 16);
        *(unsigned int*)((unsigned short*)outp + (size_t)n * 128 + lane * 2) = pk;
    }
}

extern "C" void kernel_launch(void* const* d_in, const int* in_sizes, int n_in,
                              void* d_out, int out_size, void* d_ws, size_t ws_size,
                              hipStream_t stream) {
    const void* x    = d_in[0];
    const int*  ei   = (const int*)d_in[1];
    const void* W    = d_in[2];
    const void* atts = d_in[3];
    const void* attd = d_in[4];
    const void* bias = d_in[5];

    int N = in_sizes[0] / 128;
    int E = in_sizes[1] / 2;
    int EL = E + N;

    char* p = (char*)d_ws;
    auto alloc = [&](size_t bytes) -> char* {
        char* q = p; p += (bytes + 255) & ~(size_t)255; return q;
    };
    int* flags   = (int*)alloc(256);
    int* bsum    = (int*)alloc(2048 * 4);
    int* rowptr  = (int*)alloc((size_t)(N + 1) * 4);
    int* cursor  = (int*)alloc((size_t)N * 4);
    float* as_   = (float*)alloc((size_t)N * 2 * 4);
    float* ad_   = (float*)alloc((size_t)N * 2 * 4);
    unsigned short* wt = (unsigned short*)alloc(2 * 256 * 128 * 2);
    int* csr     = (int*)alloc((size_t)EL * 4);
    float* wbuf  = (float*)alloc((size_t)EL * 2 * 4);                     // 6.8 MB
    unsigned short* hbuf = (unsigned short*)alloc((size_t)N * 256 * 2);   // 25.6 MB, last

    k_probe_zero<<<(N + 255) / 256, 256, 0, stream>>>((const unsigned int*)x, ei, flags, cursor, N);
    k_count<<<(EL + 255) / 256, 256, 0, stream>>>(ei, E, N, flags, cursor);
    int nb = (N + 1023) / 1024;
    k_scan1<<<nb, 1024, 0, stream>>>(cursor, rowptr, bsum, N);
    k_scan2<<<1, 256, 0, stream>>>(bsum, nb);
    k_scan3<<<(N + 256) / 256, 256, 0, stream>>>(rowptr, bsum, cursor, N);
    k_scatter<<<(EL + 255) / 256, 256, 0, stream>>>(ei, E, N, flags, cursor, csr);
    k_transpose<<<256, 256, 0, stream>>>(W, wt, flags);

    int mtiles = (N + 15) / 16;
    int ngrp = (N + 3) / 4;
    for (int l = 0; l < 2; l++) {
        const void* xin = (l == 0) ? x : (const void*)d_out;
        k_gemm_alpha<<<mtiles, 256, 0, stream>>>(xin, wt + l * 32768, atts, attd, l,
                                                 hbuf, as_, ad_, N, flags);
        k_weights<<<ngrp, 256, 0, stream>>>(as_, ad_, rowptr, csr, wbuf, N, EL);
        k_gather<<<ngrp * 8, 256, 0, stream>>>(hbuf, wbuf, rowptr, csr, bias, l, flags,
                                               d_out, N, EL);
        k_norm<<<ngrp, 256, 0, stream>>>(d_out, flags, N);
    }
}

// Round 8
// 388.622 us; speedup vs baseline: 1.6059x; 1.6059x over previous
//
#include <hip/hip_runtime.h>

// GAT, 2 layers, H=2 heads, D=C=128, concat=False (head mean), L2 normalize after each layer.
// Float tensors: fp32 OR bf16 (runtime-probed). edge_index: int32 OR int64 (runtime-probed).
// Internal h-matrix bf16 row-major [N][256]. R8: gemm epilogue LDS-staged -> vectorized stores.

using short8  = __attribute__((ext_vector_type(8))) short;
using float4v = __attribute__((ext_vector_type(4))) float;

static __device__ __forceinline__ float bf2f(unsigned int u16) {
    union { unsigned int i; float f; } v; v.i = u16 << 16; return v.f;
}
static __device__ __forceinline__ float bflo(unsigned int p){
    union { unsigned int i; float f; } v; v.i = p << 16; return v.f;
}
static __device__ __forceinline__ float bfhi(unsigned int p){
    union { unsigned int i; float f; } v; v.i = p & 0xffff0000u; return v.f;
}
static __device__ __forceinline__ unsigned short f2bf(float f) {
    union { float f; unsigned int i; } v; v.f = f;
    unsigned int x = v.i;
    x += 0x7fffu + ((x >> 16) & 1u);   // RNE
    return (unsigned short)(x >> 16);
}
static __device__ __forceinline__ float leaky(float x){ return x > 0.f ? x : 0.2f * x; }

// ---------------- probe dtypes + zero cursor (fused) ----------------
__global__ __launch_bounds__(256) void k_probe_zero(const unsigned int* __restrict__ xw,
                                                    const int* __restrict__ ei,
                                                    int* __restrict__ flags,
                                                    int* __restrict__ cursor, int N) {
    int i = blockIdx.x * 256 + threadIdx.x;
    if (i < N) cursor[i] = 0;
    if (blockIdx.x == 0) {
        __shared__ int insane, oddnz;
        int t = threadIdx.x;
        if (t == 0) { insane = 0; oddnz = 0; }
        __syncthreads();
        unsigned int w = xw[t];
        if (((w >> 7) & 0xFFu) >= 154u) atomicOr(&insane, 1);
        if (ei[2 * t + 1] != 0) atomicOr(&oddnz, 1);
        __syncthreads();
        if (t == 0) { flags[0] = insane ? 1 : 0; flags[1] = oddnz ? 0 : 1; }
    }
}

// ---------------- W -> WT (bf16): WT[l][n][k] = W[l][k][n] ----------------
__global__ __launch_bounds__(256) void k_transpose(const void* __restrict__ W,
                                                   unsigned short* __restrict__ WT,
                                                   const int* __restrict__ flags) {
    int fx = flags[0];
    int idx = blockIdx.x * 256 + threadIdx.x;
    int layer = idx >> 15;
    int rem = idx & 32767;
    int k = rem >> 8, n = rem & 255;
    int srci = layer * 32768 + k * 256 + n;
    unsigned short v;
    if (fx) v = f2bf(((const float*)W)[srci]);
    else    v = ((const unsigned short*)W)[srci];
    WT[layer * 32768 + n * 128 + k] = v;
}

// ---------------- fused GEMM + alpha: Hb = X@W (bf16), as_/ad_ = (h . att) per head ----------
// one block per 16-row tile; wave w computes col tiles [4w,4w+4) (one head per wave).
// Epilogue: acc -> wave-private LDS tile (16 rows x 64 cols bf16) -> 2x dwordx4 stores/lane.
__global__ __launch_bounds__(256) void k_gemm_alpha(const void* __restrict__ X,
                                                    const unsigned short* __restrict__ WT,
                                                    const void* __restrict__ atts,
                                                    const void* __restrict__ attd,
                                                    int layer,
                                                    unsigned short* __restrict__ Hb,
                                                    float* __restrict__ as_, float* __restrict__ ad_,
                                                    int N, const int* __restrict__ flags) {
    __shared__ float lds_s[4][16], lds_d[4][16];
    __shared__ unsigned short cbuf[4][16][72];   // 72-short row stride: 16B-aligned, bank-skewed
    int fx = flags[0];
    int mt = blockIdx.x;
    int wave = threadIdx.x >> 6;
    int lane = threadIdx.x & 63;
    int r16 = lane & 15, quad = lane >> 4;
    int m0 = mt << 4;
    int arow = m0 + r16; if (arow >= N) arow = N - 1;
    short8 a[4];
    if (fx) {
        const float* Xf = (const float*)X;
#pragma unroll
        for (int kk = 0; kk < 4; kk++) {
            const float4v* pv = (const float4v*)(Xf + (size_t)arow * 128 + kk * 32 + quad * 8);
            float4v lo = pv[0], hi = pv[1];
            short8 t;
            t[0] = (short)f2bf(lo[0]); t[1] = (short)f2bf(lo[1]);
            t[2] = (short)f2bf(lo[2]); t[3] = (short)f2bf(lo[3]);
            t[4] = (short)f2bf(hi[0]); t[5] = (short)f2bf(hi[1]);
            t[6] = (short)f2bf(hi[2]); t[7] = (short)f2bf(hi[3]);
            a[kk] = t;
        }
    } else {
        const unsigned short* Xh = (const unsigned short*)X;
#pragma unroll
        for (int kk = 0; kk < 4; kk++)
            a[kk] = *(const short8*)(Xh + (size_t)arow * 128 + kk * 32 + quad * 8);
    }
    int head = wave >> 1;
    float ps[4] = {0.f, 0.f, 0.f, 0.f}, pd[4] = {0.f, 0.f, 0.f, 0.f};
#pragma unroll
    for (int nn = 0; nn < 4; nn++) {
        int nt = wave * 4 + nn;
        float4v acc = {0.f, 0.f, 0.f, 0.f};
#pragma unroll
        for (int kk = 0; kk < 4; kk++) {
            short8 b = *(const short8*)(WT + (nt * 16 + r16) * 128 + kk * 32 + quad * 8);
            acc = __builtin_amdgcn_mfma_f32_16x16x32_bf16(a[kk], b, acc, 0, 0, 0);
        }
        int c = (nt * 16 + r16) & 127;
        float sa, da;
        if (fx) {
            sa = ((const float*)atts)[layer * 256 + head * 128 + c];
            da = ((const float*)attd)[layer * 256 + head * 128 + c];
        } else {
            sa = bf2f(((const unsigned short*)atts)[layer * 256 + head * 128 + c]);
            da = bf2f(((const unsigned short*)attd)[layer * 256 + head * 128 + c]);
        }
#pragma unroll
        for (int r = 0; r < 4; r++) {
            // C/D: col=lane&15, row=quad*4+r  [m89]; stage transposed write in LDS
            cbuf[wave][quad * 4 + r][nn * 16 + r16] = f2bf(acc[r]);
            ps[r] += acc[r] * sa;
            pd[r] += acc[r] * da;
        }
    }
    // wave-private LDS tile -> coalesced dwordx4 stores (8 rows x 128B per instr)
#pragma unroll
    for (int it = 0; it < 2; it++) {
        int idx = it * 64 + lane;          // 0..127
        int row = idx >> 3, chunk = idx & 7;
        uint4 v = *(const uint4*)&cbuf[wave][row][chunk * 8];
        int grow = m0 + row;
        if (grow < N)
            *(uint4*)(Hb + (size_t)grow * 256 + wave * 64 + chunk * 8) = v;
    }
    // alpha reduction (over 16 cols within each quad group), then cross-wave via LDS
#pragma unroll
    for (int m = 1; m < 16; m <<= 1) {
#pragma unroll
        for (int r = 0; r < 4; r++) {
            ps[r] += __shfl_xor(ps[r], m);
            pd[r] += __shfl_xor(pd[r], m);
        }
    }
    if (r16 == 0) {
#pragma unroll
        for (int r = 0; r < 4; r++) {
            lds_s[wave][quad * 4 + r] = ps[r];
            lds_d[wave][quad * 4 + r] = pd[r];
        }
    }
    __syncthreads();
    if (threadIdx.x < 16) {
        int row = m0 + threadIdx.x;
        if (row < N) {
            float2 sv = { lds_s[0][threadIdx.x] + lds_s[1][threadIdx.x],
                          lds_s[2][threadIdx.x] + lds_s[3][threadIdx.x] };
            float2 dv = { lds_d[0][threadIdx.x] + lds_d[1][threadIdx.x],
                          lds_d[2][threadIdx.x] + lds_d[3][threadIdx.x] };
            *(float2*)(as_ + 2 * row) = sv;   // [head0, head1]
            *(float2*)(ad_ + 2 * row) = dv;
        }
    }
}

// ---------------- CSR build ----------------
static __device__ __forceinline__ int edge_dst(const int* ei, int E, int i, int is64) {
    return is64 ? ei[2 * E + 2 * i] : ei[E + i];
}
static __device__ __forceinline__ int edge_src(const int* ei, int E, int i, int is64) {
    return is64 ? ei[2 * i] : ei[i];
}

__global__ __launch_bounds__(256) void k_count(const int* __restrict__ ei, int E, int N,
                                               const int* __restrict__ flags, int* deg) {
    int i = blockIdx.x * 256 + threadIdx.x;
    if (i >= E + N) return;
    int dst;
    if (i < E) { dst = edge_dst(ei, E, i, flags[1]); if ((unsigned)dst >= (unsigned)N) dst = 0; }
    else dst = i - E;
    atomicAdd(&deg[dst], 1);
}

__global__ __launch_bounds__(1024) void k_scan1(const int* __restrict__ deg, int* __restrict__ excl,
                                                int* __restrict__ bsum, int n) {
    __shared__ int buf[1024];
    int t = threadIdx.x;
    int i = blockIdx.x * 1024 + t;
    int v = (i < n) ? deg[i] : 0;
    int x = v; buf[t] = v; __syncthreads();
    for (int off = 1; off < 1024; off <<= 1) {
        int add = (t >= off) ? buf[t - off] : 0;
        __syncthreads();
        x += add; buf[t] = x;
        __syncthreads();
    }
    if (i < n) excl[i] = x - v;
    if (t == 1023) bsum[blockIdx.x] = x;
}

__global__ __launch_bounds__(256) void k_scan2(int* bsum, int nb) {
    __shared__ int buf[256];
    int t = threadIdx.x;
    int v = (t < nb) ? bsum[t] : 0;
    int x = v; buf[t] = v; __syncthreads();
    for (int off = 1; off < 256; off <<= 1) {
        int add = (t >= off) ? buf[t - off] : 0;
        __syncthreads();
        x += add; buf[t] = x;
        __syncthreads();
    }
    if (t < nb) bsum[t] = x - v;
    if (t == nb - 1) bsum[nb] = x;
}

__global__ __launch_bounds__(256) void k_scan3(int* __restrict__ rowptr, const int* __restrict__ bsum,
                                               int* __restrict__ cursor, int N) {
    int i = blockIdx.x * 256 + threadIdx.x;
    if (i < N) {
        int r = rowptr[i] + bsum[i >> 10];
        rowptr[i] = r;
        cursor[i] = r;
    } else if (i == N) {
        rowptr[N] = bsum[(N + 1023) >> 10];
    }
}

__global__ __launch_bounds__(256) void k_scatter(const int* __restrict__ ei, int E, int N,
                                                 const int* __restrict__ flags,
                                                 int* __restrict__ cursor, int* __restrict__ csr) {
    int i = blockIdx.x * 256 + threadIdx.x;
    if (i >= E + N) return;
    int src, dst;
    if (i < E) {
        int is64 = flags[1];
        src = edge_src(ei, E, i, is64);
        dst = edge_dst(ei, E, i, is64);
        if ((unsigned)src >= (unsigned)N) src = 0;
        if ((unsigned)dst >= (unsigned)N) dst = 0;
    } else src = dst = i - E;
    int pos = atomicAdd(&cursor[dst], 1);
    csr[pos] = src;
}

// ---------------- per-dst softmax + aggregation + head-mean + bias + L2 norm ----------------
// one wave per node; fast path (deg<=64): single fused sweep; 4 lane-groups of 16 gather
// one edge each (2x dwordx4/lane, 512B/edge), 4 edges in flight.
static __device__ __forceinline__ void acc8(float* A, float w, uint4 q) {
    A[0] += w * bflo(q.x); A[1] += w * bfhi(q.x);
    A[2] += w * bflo(q.y); A[3] += w * bfhi(q.y);
    A[4] += w * bflo(q.z); A[5] += w * bfhi(q.z);
    A[6] += w * bflo(q.w); A[7] += w * bfhi(q.w);
}

__global__ __launch_bounds__(256) void k_aggregate(const unsigned short* __restrict__ Hb,
                                                   const float* __restrict__ as_, const float* __restrict__ ad_,
                                                   const int* __restrict__ rowptr, const int* __restrict__ csr,
                                                   const void* __restrict__ bias, int layer,
                                                   const int* __restrict__ flags,
                                                   void* __restrict__ outp, int N, int EL) {
    int fx = flags[0];
    int n = blockIdx.x * 4 + (threadIdx.x >> 6);
    if (n >= N) return;
    int lane = threadIdx.x & 63;
    int g = lane >> 4;       // group 0..3
    int gl = lane & 15;      // lane in group; owns channels [gl*8, gl*8+8) of each head
    int start = rowptr[n], end = rowptr[n + 1];
    if (start < 0) start = 0;
    if (end > EL) end = EL;
    if (end < start) end = start;
    float2 adv = *(const float2*)(ad_ + 2 * n);
    float ad0 = adv.x, ad1 = adv.y;

    float acc0[8] = {0,0,0,0,0,0,0,0}, acc1[8] = {0,0,0,0,0,0,0,0};
    float z0, z1;
    int deg = end - start;

    if (deg <= 64) {
        int i = start + lane;
        bool act = i < end;
        int s = 0; float l0 = -1e30f, l1 = -1e30f;
        if (act) {
            s = csr[i]; if ((unsigned)s >= (unsigned)N) s = 0;
            float2 av = *(const float2*)(as_ + 2 * s);
            l0 = leaky(av.x + ad0); l1 = leaky(av.y + ad1);
        }
        float m0 = l0, m1 = l1;
#pragma unroll
        for (int m = 1; m < 64; m <<= 1) { m0 = fmaxf(m0, __shfl_xor(m0, m)); m1 = fmaxf(m1, __shfl_xor(m1, m)); }
        float w0 = act ? __expf(l0 - m0) : 0.f;
        float w1 = act ? __expf(l1 - m1) : 0.f;
        z0 = w0; z1 = w1;
#pragma unroll
        for (int m = 1; m < 64; m <<= 1) { z0 += __shfl_xor(z0, m); z1 += __shfl_xor(z1, m); }
#pragma unroll 2
        for (int j = 0; 4 * j < deg; j++) {
            int e = 4 * j + g;
            int sq    = __shfl(s, e);
            float wq0 = __shfl(w0, e);
            float wq1 = __shfl(w1, e);
            if (e < deg) {
                const unsigned short* row = Hb + ((size_t)sq << 8);
                uint4 q0 = *(const uint4*)(row + gl * 8);
                uint4 q1 = *(const uint4*)(row + 128 + gl * 8);
                acc8(acc0, wq0, q0);
                acc8(acc1, wq1, q1);
            }
        }
    } else {
        float m0 = -1e30f, m1 = -1e30f;
        for (int i = start + lane; i < end; i += 64) {
            int s = csr[i]; if ((unsigned)s >= (unsigned)N) s = 0;
            float2 av = *(const float2*)(as_ + 2 * s);
            m0 = fmaxf(m0, leaky(av.x + ad0));
            m1 = fmaxf(m1, leaky(av.y + ad1));
        }
#pragma unroll
        for (int m = 1; m < 64; m <<= 1) { m0 = fmaxf(m0, __shfl_xor(m0, m)); m1 = fmaxf(m1, __shfl_xor(m1, m)); }
        z0 = 0.f; z1 = 0.f;
        for (int t = start; t < end; t += 64) {
            int i = t + lane;
            int s = 0; float w0 = 0.f, w1 = 0.f;
            if (i < end) {
                s = csr[i]; if ((unsigned)s >= (unsigned)N) s = 0;
                float2 av = *(const float2*)(as_ + 2 * s);
                w0 = __expf(leaky(av.x + ad0) - m0);
                w1 = __expf(leaky(av.y + ad1) - m1);
                z0 += w0; z1 += w1;
            }
            int cnt = end - t; if (cnt > 64) cnt = 64;
            for (int j = 0; 4 * j < cnt; j++) {
                int e = 4 * j + g;
                int sq    = __shfl(s, e);
                float wq0 = __shfl(w0, e);
                float wq1 = __shfl(w1, e);
                if (e < cnt) {
                    const unsigned short* row = Hb + ((size_t)sq << 8);
                    uint4 q0 = *(const uint4*)(row + gl * 8);
                    uint4 q1 = *(const uint4*)(row + 128 + gl * 8);
                    acc8(acc0, wq0, q0);
                    acc8(acc1, wq1, q1);
                }
            }
        }
#pragma unroll
        for (int m = 1; m < 64; m <<= 1) { z0 += __shfl_xor(z0, m); z1 += __shfl_xor(z1, m); }
    }

    float inv0 = 1.f / (z0 + 1e-16f), inv1 = 1.f / (z1 + 1e-16f);
#pragma unroll
    for (int k = 0; k < 8; k++) {
        acc0[k] += __shfl_xor(acc0[k], 16); acc0[k] += __shfl_xor(acc0[k], 32);
        acc1[k] += __shfl_xor(acc1[k], 16); acc1[k] += __shfl_xor(acc1[k], 32);
    }

    float v[8];
    if (fx) {
        const float* bf = (const float*)bias + layer * 128 + gl * 8;
#pragma unroll
        for (int k = 0; k < 8; k++) v[k] = 0.5f * (acc0[k] * inv0 + acc1[k] * inv1) + bf[k];
    } else {
        const unsigned short* bh = (const unsigned short*)bias + layer * 128 + gl * 8;
        uint4 bv = *(const uint4*)bh;
        float bfv[8] = { bflo(bv.x), bfhi(bv.x), bflo(bv.y), bfhi(bv.y),
                         bflo(bv.z), bfhi(bv.z), bflo(bv.w), bfhi(bv.w) };
#pragma unroll
        for (int k = 0; k < 8; k++) v[k] = 0.5f * (acc0[k] * inv0 + acc1[k] * inv1) + bfv[k];
    }

    float ss = 0.f;
#pragma unroll
    for (int k = 0; k < 8; k++) ss += v[k] * v[k];
#pragma unroll
    for (int m = 1; m < 16; m <<= 1) ss += __shfl_xor(ss, m);
    float inv = 1.f / fmaxf(sqrtf(ss), 1e-12f);

    if (lane < 16) {
        if (fx) {
            float* op = (float*)outp + (size_t)n * 128 + gl * 8;
            float4 o0 = { v[0] * inv, v[1] * inv, v[2] * inv, v[3] * inv };
            float4 o1 = { v[4] * inv, v[5] * inv, v[6] * inv, v[7] * inv };
            *(float4*)op = o0;
            *(float4*)(op + 4) = o1;
        } else {
            unsigned short* op = (unsigned short*)outp + (size_t)n * 128 + gl * 8;
            uint4 pk;
            pk.x = (unsigned int)f2bf(v[0] * inv) | ((unsigned int)f2bf(v[1] * inv) << 16);
            pk.y = (unsigned int)f2bf(v[2] * inv) | ((unsigned int)f2bf(v[3] * inv) << 16);
            pk.z = (unsigned int)f2bf(v[4] * inv) | ((unsigned int)f2bf(v[5] * inv) << 16);
            pk.w = (unsigned int)f2bf(v[6] * inv) | ((unsigned int)f2bf(v[7] * inv) << 16);
            *(uint4*)op = pk;
        }
    }
}

extern "C" void kernel_launch(void* const* d_in, const int* in_sizes, int n_in,
                              void* d_out, int out_size, void* d_ws, size_t ws_size,
                              hipStream_t stream) {
    const void* x    = d_in[0];
    const int*  ei   = (const int*)d_in[1];
    const void* W    = d_in[2];
    const void* atts = d_in[3];
    const void* attd = d_in[4];
    const void* bias = d_in[5];

    int N = in_sizes[0] / 128;
    int E = in_sizes[1] / 2;
    int EL = E + N;

    char* p = (char*)d_ws;
    auto alloc = [&](size_t bytes) -> char* {
        char* q = p; p += (bytes + 255) & ~(size_t)255; return q;
    };
    int* flags   = (int*)alloc(256);
    int* bsum    = (int*)alloc(2048 * 4);
    int* rowptr  = (int*)alloc((size_t)(N + 1) * 4);
    int* cursor  = (int*)alloc((size_t)N * 4);
    float* as_   = (float*)alloc((size_t)N * 2 * 4);
    float* ad_   = (float*)alloc((size_t)N * 2 * 4);
    unsigned short* wt = (unsigned short*)alloc(2 * 256 * 128 * 2);
    int* csr     = (int*)alloc((size_t)EL * 4);
    unsigned short* hbuf = (unsigned short*)alloc((size_t)N * 256 * 2);   // 25.6 MB, last

    k_probe_zero<<<(N + 255) / 256, 256, 0, stream>>>((const unsigned int*)x, ei, flags, cursor, N);
    k_count<<<(EL + 255) / 256, 256, 0, stream>>>(ei, E, N, flags, cursor);
    int nb = (N + 1023) / 1024;
    k_scan1<<<nb, 1024, 0, stream>>>(cursor, rowptr, bsum, N);
    k_scan2<<<1, 256, 0, stream>>>(bsum, nb);
    k_scan3<<<(N + 256) / 256, 256, 0, stream>>>(rowptr, bsum, cursor, N);
    k_scatter<<<(EL + 255) / 256, 256, 0, stream>>>(ei, E, N, flags, cursor, csr);
    k_transpose<<<256, 256, 0, stream>>>(W, wt, flags);

    int mtiles = (N + 15) / 16;
    for (int l = 0; l < 2; l++) {
        const void* xin = (l == 0) ? x : (const void*)d_out;
        k_gemm_alpha<<<mtiles, 256, 0, stream>>>(xin, wt + l * 32768, atts, attd, l,
                                                 hbuf, as_, ad_, N, flags);
        k_aggregate<<<(N + 3) / 4, 256, 0, stream>>>(hbuf, as_, ad_, rowptr, csr, bias, l, flags,
                                                     d_out, N, EL);
    }
}

// Round 9
// 357.998 us; speedup vs baseline: 1.7433x; 1.0855x over previous
//
#include <hip/hip_runtime.h>

// GAT, 2 layers, H=2 heads, D=C=128, concat=False (head mean), L2 normalize after each layer.
// Float tensors: fp32 OR bf16 (runtime-probed). edge_index: int32 OR int64 (runtime-probed).
// Internal h-matrix bf16 row-major [N][256].
// R9: CSR replaced by single-pass fixed-capacity buckets (48/node) + spill list (never hit
// in practice, handled correctly if it is). Kills count+scan1/2/3 kernels.

#define CAP 48
#define SPILLCAP 65536

using short8  = __attribute__((ext_vector_type(8))) short;
using float4v = __attribute__((ext_vector_type(4))) float;

static __device__ __forceinline__ float bf2f(unsigned int u16) {
    union { unsigned int i; float f; } v; v.i = u16 << 16; return v.f;
}
static __device__ __forceinline__ float bflo(unsigned int p){
    union { unsigned int i; float f; } v; v.i = p << 16; return v.f;
}
static __device__ __forceinline__ float bfhi(unsigned int p){
    union { unsigned int i; float f; } v; v.i = p & 0xffff0000u; return v.f;
}
static __device__ __forceinline__ unsigned short f2bf(float f) {
    union { float f; unsigned int i; } v; v.f = f;
    unsigned int x = v.i;
    x += 0x7fffu + ((x >> 16) & 1u);   // RNE
    return (unsigned short)(x >> 16);
}
static __device__ __forceinline__ float leaky(float x){ return x > 0.f ? x : 0.2f * x; }

// ---------------- probe dtypes + zero cnt/spillcnt (fused) ----------------
// flags[0]=1 iff x fp32; flags[1]=1 iff edge_index int64; flags[2]=spill counter.
__global__ __launch_bounds__(256) void k_probe_zero(const unsigned int* __restrict__ xw,
                                                    const int* __restrict__ ei,
                                                    int* __restrict__ flags,
                                                    int* __restrict__ cnt, int N) {
    int i = blockIdx.x * 256 + threadIdx.x;
    if (i < N) cnt[i] = 0;
    if (blockIdx.x == 0) {
        __shared__ int insane, oddnz;
        int t = threadIdx.x;
        if (t == 0) { insane = 0; oddnz = 0; }
        __syncthreads();
        unsigned int w = xw[t];
        if (((w >> 7) & 0xFFu) >= 154u) atomicOr(&insane, 1);
        if (ei[2 * t + 1] != 0) atomicOr(&oddnz, 1);
        __syncthreads();
        if (t == 0) { flags[0] = insane ? 1 : 0; flags[1] = oddnz ? 0 : 1; flags[2] = 0; }
    }
}

// ---------------- W -> WT (bf16): WT[l][n][k] = W[l][k][n] ----------------
__global__ __launch_bounds__(256) void k_transpose(const void* __restrict__ W,
                                                   unsigned short* __restrict__ WT,
                                                   const int* __restrict__ flags) {
    int fx = flags[0];
    int idx = blockIdx.x * 256 + threadIdx.x;
    int layer = idx >> 15;
    int rem = idx & 32767;
    int k = rem >> 8, n = rem & 255;
    int srci = layer * 32768 + k * 256 + n;
    unsigned short v;
    if (fx) v = f2bf(((const float*)W)[srci]);
    else    v = ((const unsigned short*)W)[srci];
    WT[layer * 32768 + n * 128 + k] = v;
}

// ---------------- single-pass bucket scatter ----------------
static __device__ __forceinline__ int edge_dst(const int* ei, int E, int i, int is64) {
    return is64 ? ei[2 * E + 2 * i] : ei[E + i];
}
static __device__ __forceinline__ int edge_src(const int* ei, int E, int i, int is64) {
    return is64 ? ei[2 * i] : ei[i];
}

__global__ __launch_bounds__(256) void k_bucket(const int* __restrict__ ei, int E, int N,
                                                int* __restrict__ flags,
                                                int* __restrict__ cnt,
                                                int* __restrict__ bucket,
                                                int* __restrict__ spill) {
    int i = blockIdx.x * 256 + threadIdx.x;
    if (i >= E + N) return;
    int src, dst;
    if (i < E) {
        int is64 = flags[1];
        src = edge_src(ei, E, i, is64);
        dst = edge_dst(ei, E, i, is64);
        if ((unsigned)src >= (unsigned)N) src = 0;
        if ((unsigned)dst >= (unsigned)N) dst = 0;
    } else src = dst = i - E;   // self loop
    int pos = atomicAdd(&cnt[dst], 1);
    if (pos < CAP) {
        bucket[dst * CAP + pos] = src;
    } else {
        int sp = atomicAdd(&flags[2], 1);
        if (sp < SPILLCAP) { spill[2 * sp] = dst; spill[2 * sp + 1] = src; }
    }
}

// ---------------- fused GEMM + alpha (R8-proven) ----------------
__global__ __launch_bounds__(256) void k_gemm_alpha(const void* __restrict__ X,
                                                    const unsigned short* __restrict__ WT,
                                                    const void* __restrict__ atts,
                                                    const void* __restrict__ attd,
                                                    int layer,
                                                    unsigned short* __restrict__ Hb,
                                                    float* __restrict__ as_, float* __restrict__ ad_,
                                                    int N, const int* __restrict__ flags) {
    __shared__ float lds_s[4][16], lds_d[4][16];
    __shared__ unsigned short cbuf[4][16][72];
    int fx = flags[0];
    int mt = blockIdx.x;
    int wave = threadIdx.x >> 6;
    int lane = threadIdx.x & 63;
    int r16 = lane & 15, quad = lane >> 4;
    int m0 = mt << 4;
    int arow = m0 + r16; if (arow >= N) arow = N - 1;
    short8 a[4];
    if (fx) {
        const float* Xf = (const float*)X;
#pragma unroll
        for (int kk = 0; kk < 4; kk++) {
            const float4v* pv = (const float4v*)(Xf + (size_t)arow * 128 + kk * 32 + quad * 8);
            float4v lo = pv[0], hi = pv[1];
            short8 t;
            t[0] = (short)f2bf(lo[0]); t[1] = (short)f2bf(lo[1]);
            t[2] = (short)f2bf(lo[2]); t[3] = (short)f2bf(lo[3]);
            t[4] = (short)f2bf(hi[0]); t[5] = (short)f2bf(hi[1]);
            t[6] = (short)f2bf(hi[2]); t[7] = (short)f2bf(hi[3]);
            a[kk] = t;
        }
    } else {
        const unsigned short* Xh = (const unsigned short*)X;
#pragma unroll
        for (int kk = 0; kk < 4; kk++)
            a[kk] = *(const short8*)(Xh + (size_t)arow * 128 + kk * 32 + quad * 8);
    }
    int head = wave >> 1;
    float ps[4] = {0.f, 0.f, 0.f, 0.f}, pd[4] = {0.f, 0.f, 0.f, 0.f};
#pragma unroll
    for (int nn = 0; nn < 4; nn++) {
        int nt = wave * 4 + nn;
        float4v acc = {0.f, 0.f, 0.f, 0.f};
#pragma unroll
        for (int kk = 0; kk < 4; kk++) {
            short8 b = *(const short8*)(WT + (nt * 16 + r16) * 128 + kk * 32 + quad * 8);
            acc = __builtin_amdgcn_mfma_f32_16x16x32_bf16(a[kk], b, acc, 0, 0, 0);
        }
        int c = (nt * 16 + r16) & 127;
        float sa, da;
        if (fx) {
            sa = ((const float*)atts)[layer * 256 + head * 128 + c];
            da = ((const float*)attd)[layer * 256 + head * 128 + c];
        } else {
            sa = bf2f(((const unsigned short*)atts)[layer * 256 + head * 128 + c]);
            da = bf2f(((const unsigned short*)attd)[layer * 256 + head * 128 + c]);
        }
#pragma unroll
        for (int r = 0; r < 4; r++) {
            cbuf[wave][quad * 4 + r][nn * 16 + r16] = f2bf(acc[r]);   // C/D: col=lane&15, row=quad*4+r [m89]
            ps[r] += acc[r] * sa;
            pd[r] += acc[r] * da;
        }
    }
#pragma unroll
    for (int it = 0; it < 2; it++) {
        int idx = it * 64 + lane;
        int row = idx >> 3, chunk = idx & 7;
        uint4 v = *(const uint4*)&cbuf[wave][row][chunk * 8];
        int grow = m0 + row;
        if (grow < N)
            *(uint4*)(Hb + (size_t)grow * 256 + wave * 64 + chunk * 8) = v;
    }
#pragma unroll
    for (int m = 1; m < 16; m <<= 1) {
#pragma unroll
        for (int r = 0; r < 4; r++) {
            ps[r] += __shfl_xor(ps[r], m);
            pd[r] += __shfl_xor(pd[r], m);
        }
    }
    if (r16 == 0) {
#pragma unroll
        for (int r = 0; r < 4; r++) {
            lds_s[wave][quad * 4 + r] = ps[r];
            lds_d[wave][quad * 4 + r] = pd[r];
        }
    }
    __syncthreads();
    if (threadIdx.x < 16) {
        int row = m0 + threadIdx.x;
        if (row < N) {
            float2 sv = { lds_s[0][threadIdx.x] + lds_s[1][threadIdx.x],
                          lds_s[2][threadIdx.x] + lds_s[3][threadIdx.x] };
            float2 dv = { lds_d[0][threadIdx.x] + lds_d[1][threadIdx.x],
                          lds_d[2][threadIdx.x] + lds_d[3][threadIdx.x] };
            *(float2*)(as_ + 2 * row) = sv;
            *(float2*)(ad_ + 2 * row) = dv;
        }
    }
}

// ---------------- per-dst softmax + aggregation + head-mean + bias + L2 norm ----------------
static __device__ __forceinline__ void acc8(float* A, float w, uint4 q) {
    A[0] += w * bflo(q.x); A[1] += w * bfhi(q.x);
    A[2] += w * bflo(q.y); A[3] += w * bfhi(q.y);
    A[4] += w * bflo(q.z); A[5] += w * bfhi(q.z);
    A[6] += w * bflo(q.w); A[7] += w * bfhi(q.w);
}

__global__ __launch_bounds__(256) void k_aggregate(const unsigned short* __restrict__ Hb,
                                                   const float* __restrict__ as_, const float* __restrict__ ad_,
                                                   const int* __restrict__ cnt, const int* __restrict__ bucket,
                                                   const int* __restrict__ spill, const int* __restrict__ flags,
                                                   const void* __restrict__ bias, int layer,
                                                   void* __restrict__ outp, int N) {
    int fx = flags[0];
    int n = blockIdx.x * 4 + (threadIdx.x >> 6);
    if (n >= N) return;
    int lane = threadIdx.x & 63;
    int g = lane >> 4;       // group 0..3
    int gl = lane & 15;      // owns channels [gl*8, gl*8+8) of each head
    int deg = cnt[n];
    const int* eb = bucket + n * CAP;
    float2 adv = *(const float2*)(ad_ + 2 * n);
    float ad0 = adv.x, ad1 = adv.y;

    float acc0[8] = {0,0,0,0,0,0,0,0}, acc1[8] = {0,0,0,0,0,0,0,0};
    float z0, z1;

    if (deg <= CAP) {
        // ---- fast path: all edges in bucket, one sweep ----
        bool act = lane < deg;
        int s = 0; float l0 = -1e30f, l1 = -1e30f;
        if (act) {
            s = eb[lane]; if ((unsigned)s >= (unsigned)N) s = 0;
            float2 av = *(const float2*)(as_ + 2 * s);
            l0 = leaky(av.x + ad0); l1 = leaky(av.y + ad1);
        }
        float m0 = l0, m1 = l1;
#pragma unroll
        for (int m = 1; m < 64; m <<= 1) { m0 = fmaxf(m0, __shfl_xor(m0, m)); m1 = fmaxf(m1, __shfl_xor(m1, m)); }
        float w0 = act ? __expf(l0 - m0) : 0.f;
        float w1 = act ? __expf(l1 - m1) : 0.f;
        z0 = w0; z1 = w1;
#pragma unroll
        for (int m = 1; m < 64; m <<= 1) { z0 += __shfl_xor(z0, m); z1 += __shfl_xor(z1, m); }
#pragma unroll 2
        for (int j = 0; 4 * j < deg; j++) {
            int e = 4 * j + g;
            int sq    = __shfl(s, e);
            float wq0 = __shfl(w0, e);
            float wq1 = __shfl(w1, e);
            if (e < deg) {
                const unsigned short* row = Hb + ((size_t)sq << 8);
                uint4 q0 = *(const uint4*)(row + gl * 8);
                uint4 q1 = *(const uint4*)(row + 128 + gl * 8);
                acc8(acc0, wq0, q0);
                acc8(acc1, wq1, q1);
            }
        }
    } else {
        // ---- slow path (deg > CAP; statistically never): bucket + spill scan ----
        int sc = flags[2]; if (sc > SPILLCAP) sc = SPILLCAP;
        float m0 = -1e30f, m1 = -1e30f;
        for (int i = lane; i < CAP; i += 64) {
            int s = eb[i]; if ((unsigned)s >= (unsigned)N) s = 0;
            float2 av = *(const float2*)(as_ + 2 * s);
            m0 = fmaxf(m0, leaky(av.x + ad0));
            m1 = fmaxf(m1, leaky(av.y + ad1));
        }
        for (int i = lane; i < sc; i += 64) {
            if (spill[2 * i] == n) {
                int s = spill[2 * i + 1]; if ((unsigned)s >= (unsigned)N) s = 0;
                float2 av = *(const float2*)(as_ + 2 * s);
                m0 = fmaxf(m0, leaky(av.x + ad0));
                m1 = fmaxf(m1, leaky(av.y + ad1));
            }
        }
#pragma unroll
        for (int m = 1; m < 64; m <<= 1) { m0 = fmaxf(m0, __shfl_xor(m0, m)); m1 = fmaxf(m1, __shfl_xor(m1, m)); }
        // z + accumulate: bucket part with group structure
        z0 = 0.f; z1 = 0.f;
        {
            bool act = lane < CAP;
            int s = 0; float w0 = 0.f, w1 = 0.f;
            if (act) {
                s = eb[lane]; if ((unsigned)s >= (unsigned)N) s = 0;
                float2 av = *(const float2*)(as_ + 2 * s);
                w0 = __expf(leaky(av.x + ad0) - m0);
                w1 = __expf(leaky(av.y + ad1) - m1);
                z0 += w0; z1 += w1;
            }
            for (int j = 0; 4 * j < CAP; j++) {
                int e = 4 * j + g;
                int sq    = __shfl(s, e);
                float wq0 = __shfl(w0, e);
                float wq1 = __shfl(w1, e);
                if (e < CAP) {
                    const unsigned short* row = Hb + ((size_t)sq << 8);
                    uint4 q0 = *(const uint4*)(row + gl * 8);
                    uint4 q1 = *(const uint4*)(row + 128 + gl * 8);
                    acc8(acc0, wq0, q0);
                    acc8(acc1, wq1, q1);
                }
            }
        }
        // spill part: uniform per edge; group 0 lanes accumulate (others contribute 0)
        for (int i = 0; i < sc; i++) {
            int d = spill[2 * i];
            if (d != n) continue;
            int s = spill[2 * i + 1]; if ((unsigned)s >= (unsigned)N) s = 0;
            float2 av = *(const float2*)(as_ + 2 * s);
            float w0 = __expf(leaky(av.x + ad0) - m0);
            float w1 = __expf(leaky(av.y + ad1) - m1);
            if (lane == 0) { z0 += w0; z1 += w1; }
            if (g == 0) {
                const unsigned short* row = Hb + ((size_t)s << 8);
                uint4 q0 = *(const uint4*)(row + gl * 8);
                uint4 q1 = *(const uint4*)(row + 128 + gl * 8);
                acc8(acc0, w0, q0);
                acc8(acc1, w1, q1);
            }
        }
#pragma unroll
        for (int m = 1; m < 64; m <<= 1) { z0 += __shfl_xor(z0, m); z1 += __shfl_xor(z1, m); }
    }

    float inv0 = 1.f / (z0 + 1e-16f), inv1 = 1.f / (z1 + 1e-16f);
#pragma unroll
    for (int k = 0; k < 8; k++) {
        acc0[k] += __shfl_xor(acc0[k], 16); acc0[k] += __shfl_xor(acc0[k], 32);
        acc1[k] += __shfl_xor(acc1[k], 16); acc1[k] += __shfl_xor(acc1[k], 32);
    }

    float v[8];
    if (fx) {
        const float* bf = (const float*)bias + layer * 128 + gl * 8;
#pragma unroll
        for (int k = 0; k < 8; k++) v[k] = 0.5f * (acc0[k] * inv0 + acc1[k] * inv1) + bf[k];
    } else {
        const unsigned short* bh = (const unsigned short*)bias + layer * 128 + gl * 8;
        uint4 bv = *(const uint4*)bh;
        float bfv[8] = { bflo(bv.x), bfhi(bv.x), bflo(bv.y), bfhi(bv.y),
                         bflo(bv.z), bfhi(bv.z), bflo(bv.w), bfhi(bv.w) };
#pragma unroll
        for (int k = 0; k < 8; k++) v[k] = 0.5f * (acc0[k] * inv0 + acc1[k] * inv1) + bfv[k];
    }

    float ss = 0.f;
#pragma unroll
    for (int k = 0; k < 8; k++) ss += v[k] * v[k];
#pragma unroll
    for (int m = 1; m < 16; m <<= 1) ss += __shfl_xor(ss, m);
    float inv = 1.f / fmaxf(sqrtf(ss), 1e-12f);

    if (lane < 16) {
        if (fx) {
            float* op = (float*)outp + (size_t)n * 128 + gl * 8;
            float4 o0 = { v[0] * inv, v[1] * inv, v[2] * inv, v[3] * inv };
            float4 o1 = { v[4] * inv, v[5] * inv, v[6] * inv, v[7] * inv };
            *(float4*)op = o0;
            *(float4*)(op + 4) = o1;
        } else {
            unsigned short* op = (unsigned short*)outp + (size_t)n * 128 + gl * 8;
            uint4 pk;
            pk.x = (unsigned int)f2bf(v[0] * inv) | ((unsigned int)f2bf(v[1] * inv) << 16);
            pk.y = (unsigned int)f2bf(v[2] * inv) | ((unsigned int)f2bf(v[3] * inv) << 16);
            pk.z = (unsigned int)f2bf(v[4] * inv) | ((unsigned int)f2bf(v[5] * inv) << 16);
            pk.w = (unsigned int)f2bf(v[6] * inv) | ((unsigned int)f2bf(v[7] * inv) << 16);
            *(uint4*)op = pk;
        }
    }
}

extern "C" void kernel_launch(void* const* d_in, const int* in_sizes, int n_in,
                              void* d_out, int out_size, void* d_ws, size_t ws_size,
                              hipStream_t stream) {
    const void* x    = d_in[0];
    const int*  ei   = (const int*)d_in[1];
    const void* W    = d_in[2];
    const void* atts = d_in[3];
    const void* attd = d_in[4];
    const void* bias = d_in[5];

    int N = in_sizes[0] / 128;
    int E = in_sizes[1] / 2;

    char* p = (char*)d_ws;
    auto alloc = [&](size_t bytes) -> char* {
        char* q = p; p += (bytes + 255) & ~(size_t)255; return q;
    };
    int* flags   = (int*)alloc(256);                                   // [0]=fx [1]=is64 [2]=spillcnt
    int* cnt     = (int*)alloc((size_t)N * 4);
    float* as_   = (float*)alloc((size_t)N * 2 * 4);
    float* ad_   = (float*)alloc((size_t)N * 2 * 4);
    unsigned short* wt = (unsigned short*)alloc(2 * 256 * 128 * 2);
    int* spill   = (int*)alloc((size_t)SPILLCAP * 2 * 4);              // 512 KB
    int* bucket  = (int*)alloc((size_t)N * CAP * 4);                   // 9.6 MB
    unsigned short* hbuf = (unsigned short*)alloc((size_t)N * 256 * 2);// 25.6 MB
    // total ~36.9 MB (< 37.1 MB proven available in R7)

    k_probe_zero<<<(N + 255) / 256, 256, 0, stream>>>((const unsigned int*)x, ei, flags, cnt, N);
    k_bucket<<<(E + N + 255) / 256, 256, 0, stream>>>(ei, E, N, flags, cnt, bucket, spill);
    k_transpose<<<256, 256, 0, stream>>>(W, wt, flags);

    int mtiles = (N + 15) / 16;
    for (int l = 0; l < 2; l++) {
        const void* xin = (l == 0) ? x : (const void*)d_out;
        k_gemm_alpha<<<mtiles, 256, 0, stream>>>(xin, wt + l * 32768, atts, attd, l,
                                                 hbuf, as_, ad_, N, flags);
        k_aggregate<<<(N + 3) / 4, 256, 0, stream>>>(hbuf, as_, ad_, cnt, bucket, spill, flags,
                                                     bias, l, d_out, N);
    }
}

// Round 10
// 353.932 us; speedup vs baseline: 1.7633x; 1.0115x over previous
//
#include <hip/hip_runtime.h>

// GAT, 2 layers, H=2 heads, D=C=128, concat=False (head mean), L2 normalize after each layer.
// Float tensors: fp32 OR bf16 (runtime-probed). edge_index: int32 OR int64 (runtime-probed).
// Internal h-matrix bf16 row-major [N][256].
// R10: spill handling moved to separate k_spillfix kernel (hot aggregate lean again);
// gather loop software-pipelined (next edge-group's loads issued before current FMAs).

#define CAP 48
#define SPILLCAP 65536

using short8  = __attribute__((ext_vector_type(8))) short;
using float4v = __attribute__((ext_vector_type(4))) float;

static __device__ __forceinline__ float bf2f(unsigned int u16) {
    union { unsigned int i; float f; } v; v.i = u16 << 16; return v.f;
}
static __device__ __forceinline__ float bflo(unsigned int p){
    union { unsigned int i; float f; } v; v.i = p << 16; return v.f;
}
static __device__ __forceinline__ float bfhi(unsigned int p){
    union { unsigned int i; float f; } v; v.i = p & 0xffff0000u; return v.f;
}
static __device__ __forceinline__ unsigned short f2bf(float f) {
    union { float f; unsigned int i; } v; v.f = f;
    unsigned int x = v.i;
    x += 0x7fffu + ((x >> 16) & 1u);   // RNE
    return (unsigned short)(x >> 16);
}
static __device__ __forceinline__ float leaky(float x){ return x > 0.f ? x : 0.2f * x; }

// ---------------- probe dtypes + zero cnt/spillcnt (fused) ----------------
__global__ __launch_bounds__(256) void k_probe_zero(const unsigned int* __restrict__ xw,
                                                    const int* __restrict__ ei,
                                                    int* __restrict__ flags,
                                                    int* __restrict__ cnt, int N) {
    int i = blockIdx.x * 256 + threadIdx.x;
    if (i < N) cnt[i] = 0;
    if (blockIdx.x == 0) {
        __shared__ int insane, oddnz;
        int t = threadIdx.x;
        if (t == 0) { insane = 0; oddnz = 0; }
        __syncthreads();
        unsigned int w = xw[t];
        if (((w >> 7) & 0xFFu) >= 154u) atomicOr(&insane, 1);
        if (ei[2 * t + 1] != 0) atomicOr(&oddnz, 1);
        __syncthreads();
        if (t == 0) { flags[0] = insane ? 1 : 0; flags[1] = oddnz ? 0 : 1; flags[2] = 0; }
    }
}

// ---------------- W -> WT (bf16): WT[l][n][k] = W[l][k][n] ----------------
__global__ __launch_bounds__(256) void k_transpose(const void* __restrict__ W,
                                                   unsigned short* __restrict__ WT,
                                                   const int* __restrict__ flags) {
    int fx = flags[0];
    int idx = blockIdx.x * 256 + threadIdx.x;
    int layer = idx >> 15;
    int rem = idx & 32767;
    int k = rem >> 8, n = rem & 255;
    int srci = layer * 32768 + k * 256 + n;
    unsigned short v;
    if (fx) v = f2bf(((const float*)W)[srci]);
    else    v = ((const unsigned short*)W)[srci];
    WT[layer * 32768 + n * 128 + k] = v;
}

// ---------------- single-pass bucket scatter ----------------
static __device__ __forceinline__ int edge_dst(const int* ei, int E, int i, int is64) {
    return is64 ? ei[2 * E + 2 * i] : ei[E + i];
}
static __device__ __forceinline__ int edge_src(const int* ei, int E, int i, int is64) {
    return is64 ? ei[2 * i] : ei[i];
}

__global__ __launch_bounds__(256) void k_bucket(const int* __restrict__ ei, int E, int N,
                                                int* __restrict__ flags,
                                                int* __restrict__ cnt,
                                                int* __restrict__ bucket,
                                                int* __restrict__ spill) {
    int i = blockIdx.x * 256 + threadIdx.x;
    if (i >= E + N) return;
    int src, dst;
    if (i < E) {
        int is64 = flags[1];
        src = edge_src(ei, E, i, is64);
        dst = edge_dst(ei, E, i, is64);
        if ((unsigned)src >= (unsigned)N) src = 0;
        if ((unsigned)dst >= (unsigned)N) dst = 0;
    } else src = dst = i - E;   // self loop
    int pos = atomicAdd(&cnt[dst], 1);
    if (pos < CAP) {
        bucket[dst * CAP + pos] = src;
    } else {
        int sp = atomicAdd(&flags[2], 1);
        if (sp < SPILLCAP) { spill[2 * sp] = dst; spill[2 * sp + 1] = src; }
    }
}

// ---------------- fused GEMM + alpha (R8-proven) ----------------
__global__ __launch_bounds__(256) void k_gemm_alpha(const void* __restrict__ X,
                                                    const unsigned short* __restrict__ WT,
                                                    const void* __restrict__ atts,
                                                    const void* __restrict__ attd,
                                                    int layer,
                                                    unsigned short* __restrict__ Hb,
                                                    float* __restrict__ as_, float* __restrict__ ad_,
                                                    int N, const int* __restrict__ flags) {
    __shared__ float lds_s[4][16], lds_d[4][16];
    __shared__ unsigned short cbuf[4][16][72];
    int fx = flags[0];
    int mt = blockIdx.x;
    int wave = threadIdx.x >> 6;
    int lane = threadIdx.x & 63;
    int r16 = lane & 15, quad = lane >> 4;
    int m0 = mt << 4;
    int arow = m0 + r16; if (arow >= N) arow = N - 1;
    short8 a[4];
    if (fx) {
        const float* Xf = (const float*)X;
#pragma unroll
        for (int kk = 0; kk < 4; kk++) {
            const float4v* pv = (const float4v*)(Xf + (size_t)arow * 128 + kk * 32 + quad * 8);
            float4v lo = pv[0], hi = pv[1];
            short8 t;
            t[0] = (short)f2bf(lo[0]); t[1] = (short)f2bf(lo[1]);
            t[2] = (short)f2bf(lo[2]); t[3] = (short)f2bf(lo[3]);
            t[4] = (short)f2bf(hi[0]); t[5] = (short)f2bf(hi[1]);
            t[6] = (short)f2bf(hi[2]); t[7] = (short)f2bf(hi[3]);
            a[kk] = t;
        }
    } else {
        const unsigned short* Xh = (const unsigned short*)X;
#pragma unroll
        for (int kk = 0; kk < 4; kk++)
            a[kk] = *(const short8*)(Xh + (size_t)arow * 128 + kk * 32 + quad * 8);
    }
    int head = wave >> 1;
    float ps[4] = {0.f, 0.f, 0.f, 0.f}, pd[4] = {0.f, 0.f, 0.f, 0.f};
#pragma unroll
    for (int nn = 0; nn < 4; nn++) {
        int nt = wave * 4 + nn;
        float4v acc = {0.f, 0.f, 0.f, 0.f};
#pragma unroll
        for (int kk = 0; kk < 4; kk++) {
            short8 b = *(const short8*)(WT + (nt * 16 + r16) * 128 + kk * 32 + quad * 8);
            acc = __builtin_amdgcn_mfma_f32_16x16x32_bf16(a[kk], b, acc, 0, 0, 0);
        }
        int c = (nt * 16 + r16) & 127;
        float sa, da;
        if (fx) {
            sa = ((const float*)atts)[layer * 256 + head * 128 + c];
            da = ((const float*)attd)[layer * 256 + head * 128 + c];
        } else {
            sa = bf2f(((const unsigned short*)atts)[layer * 256 + head * 128 + c]);
            da = bf2f(((const unsigned short*)attd)[layer * 256 + head * 128 + c]);
        }
#pragma unroll
        for (int r = 0; r < 4; r++) {
            cbuf[wave][quad * 4 + r][nn * 16 + r16] = f2bf(acc[r]);   // C/D: col=lane&15, row=quad*4+r [m89]
            ps[r] += acc[r] * sa;
            pd[r] += acc[r] * da;
        }
    }
#pragma unroll
    for (int it = 0; it < 2; it++) {
        int idx = it * 64 + lane;
        int row = idx >> 3, chunk = idx & 7;
        uint4 v = *(const uint4*)&cbuf[wave][row][chunk * 8];
        int grow = m0 + row;
        if (grow < N)
            *(uint4*)(Hb + (size_t)grow * 256 + wave * 64 + chunk * 8) = v;
    }
#pragma unroll
    for (int m = 1; m < 16; m <<= 1) {
#pragma unroll
        for (int r = 0; r < 4; r++) {
            ps[r] += __shfl_xor(ps[r], m);
            pd[r] += __shfl_xor(pd[r], m);
        }
    }
    if (r16 == 0) {
#pragma unroll
        for (int r = 0; r < 4; r++) {
            lds_s[wave][quad * 4 + r] = ps[r];
            lds_d[wave][quad * 4 + r] = pd[r];
        }
    }
    __syncthreads();
    if (threadIdx.x < 16) {
        int row = m0 + threadIdx.x;
        if (row < N) {
            float2 sv = { lds_s[0][threadIdx.x] + lds_s[1][threadIdx.x],
                          lds_s[2][threadIdx.x] + lds_s[3][threadIdx.x] };
            float2 dv = { lds_d[0][threadIdx.x] + lds_d[1][threadIdx.x],
                          lds_d[2][threadIdx.x] + lds_d[3][threadIdx.x] };
            *(float2*)(as_ + 2 * row) = sv;
            *(float2*)(ad_ + 2 * row) = dv;
        }
    }
}

// ---------------- hot aggregate: deg<=CAP only; pipelined gather ----------------
static __device__ __forceinline__ void acc8(float* A, float w, uint4 q) {
    A[0] += w * bflo(q.x); A[1] += w * bfhi(q.x);
    A[2] += w * bflo(q.y); A[3] += w * bfhi(q.y);
    A[4] += w * bflo(q.z); A[5] += w * bfhi(q.z);
    A[6] += w * bflo(q.w); A[7] += w * bfhi(q.w);
}

__global__ __launch_bounds__(256) void k_aggregate(const unsigned short* __restrict__ Hb,
                                                   const float* __restrict__ as_, const float* __restrict__ ad_,
                                                   const int* __restrict__ cnt, const int* __restrict__ bucket,
                                                   const void* __restrict__ bias, int layer,
                                                   const int* __restrict__ flags,
                                                   void* __restrict__ outp, int N) {
    int fx = flags[0];
    int n = blockIdx.x * 4 + (threadIdx.x >> 6);
    if (n >= N) return;
    int deg = cnt[n];
    if (deg > CAP) return;           // handled by k_spillfix
    int lane = threadIdx.x & 63;
    int g = lane >> 4;
    int gl = lane & 15;              // owns channels [gl*8, gl*8+8) of each head
    const int* eb = bucket + n * CAP;
    float2 adv = *(const float2*)(ad_ + 2 * n);
    float ad0 = adv.x, ad1 = adv.y;

    // softmax over bucket (single sweep: deg <= 48 <= 64 lanes)
    bool act = lane < deg;
    int s = 0; float l0 = -1e30f, l1 = -1e30f;
    if (act) {
        s = eb[lane]; if ((unsigned)s >= (unsigned)N) s = 0;
        float2 av = *(const float2*)(as_ + 2 * s);
        l0 = leaky(av.x + ad0); l1 = leaky(av.y + ad1);
    }
    float m0 = l0, m1 = l1;
#pragma unroll
    for (int m = 1; m < 64; m <<= 1) { m0 = fmaxf(m0, __shfl_xor(m0, m)); m1 = fmaxf(m1, __shfl_xor(m1, m)); }
    float w0 = act ? __expf(l0 - m0) : 0.f;
    float w1 = act ? __expf(l1 - m1) : 0.f;
    float z0 = w0, z1 = w1;
#pragma unroll
    for (int m = 1; m < 64; m <<= 1) { z0 += __shfl_xor(z0, m); z1 += __shfl_xor(z1, m); }

    // pipelined gather: 4 edge-groups; loads for group j+1 issue before FMAs of j
    float acc0[8] = {0,0,0,0,0,0,0,0}, acc1[8] = {0,0,0,0,0,0,0,0};
    int e = g;
    bool v = e < deg;
    float wq0 = __shfl(w0, e), wq1 = __shfl(w1, e);
    int sq = __shfl(s, e);
    uint4 q0, q1;
    if (v) {
        const unsigned short* row = Hb + ((size_t)sq << 8);
        q0 = *(const uint4*)(row + gl * 8);
        q1 = *(const uint4*)(row + 128 + gl * 8);
    }
    while (v) {
        int en = e + 4;
        bool vn = en < deg;
        float wn0 = __shfl(w0, en & 63), wn1 = __shfl(w1, en & 63);
        int sn = __shfl(s, en & 63);
        uint4 p0, p1;
        if (vn) {
            const unsigned short* row = Hb + ((size_t)sn << 8);
            p0 = *(const uint4*)(row + gl * 8);
            p1 = *(const uint4*)(row + 128 + gl * 8);
        }
        acc8(acc0, wq0, q0);
        acc8(acc1, wq1, q1);
        e = en; v = vn; wq0 = wn0; wq1 = wn1; q0 = p0; q1 = p1;
    }

    float inv0 = 1.f / (z0 + 1e-16f), inv1 = 1.f / (z1 + 1e-16f);
#pragma unroll
    for (int k = 0; k < 8; k++) {
        acc0[k] += __shfl_xor(acc0[k], 16); acc0[k] += __shfl_xor(acc0[k], 32);
        acc1[k] += __shfl_xor(acc1[k], 16); acc1[k] += __shfl_xor(acc1[k], 32);
    }

    float vv[8];
    if (fx) {
        const float* bf = (const float*)bias + layer * 128 + gl * 8;
#pragma unroll
        for (int k = 0; k < 8; k++) vv[k] = 0.5f * (acc0[k] * inv0 + acc1[k] * inv1) + bf[k];
    } else {
        const unsigned short* bh = (const unsigned short*)bias + layer * 128 + gl * 8;
        uint4 bv = *(const uint4*)bh;
        float bfv[8] = { bflo(bv.x), bfhi(bv.x), bflo(bv.y), bfhi(bv.y),
                         bflo(bv.z), bfhi(bv.z), bflo(bv.w), bfhi(bv.w) };
#pragma unroll
        for (int k = 0; k < 8; k++) vv[k] = 0.5f * (acc0[k] * inv0 + acc1[k] * inv1) + bfv[k];
    }

    float ss = 0.f;
#pragma unroll
    for (int k = 0; k < 8; k++) ss += vv[k] * vv[k];
#pragma unroll
    for (int m = 1; m < 16; m <<= 1) ss += __shfl_xor(ss, m);
    float inv = 1.f / fmaxf(sqrtf(ss), 1e-12f);

    if (lane < 16) {
        if (fx) {
            float* op = (float*)outp + (size_t)n * 128 + gl * 8;
            float4 o0 = { vv[0] * inv, vv[1] * inv, vv[2] * inv, vv[3] * inv };
            float4 o1 = { vv[4] * inv, vv[5] * inv, vv[6] * inv, vv[7] * inv };
            *(float4*)op = o0;
            *(float4*)(op + 4) = o1;
        } else {
            unsigned short* op = (unsigned short*)outp + (size_t)n * 128 + gl * 8;
            uint4 pk;
            pk.x = (unsigned int)f2bf(vv[0] * inv) | ((unsigned int)f2bf(vv[1] * inv) << 16);
            pk.y = (unsigned int)f2bf(vv[2] * inv) | ((unsigned int)f2bf(vv[3] * inv) << 16);
            pk.z = (unsigned int)f2bf(vv[4] * inv) | ((unsigned int)f2bf(vv[5] * inv) << 16);
            pk.w = (unsigned int)f2bf(vv[6] * inv) | ((unsigned int)f2bf(vv[7] * inv) << 16);
            *(uint4*)op = pk;
        }
    }
}

// ---------------- spill fix: only nodes with deg > CAP (statistically never) ----------------
__global__ __launch_bounds__(256) void k_spillfix(const unsigned short* __restrict__ Hb,
                                                  const float* __restrict__ as_, const float* __restrict__ ad_,
                                                  const int* __restrict__ cnt, const int* __restrict__ bucket,
                                                  const int* __restrict__ spill, const int* __restrict__ flags,
                                                  const void* __restrict__ bias, int layer,
                                                  void* __restrict__ outp, int N) {
    int fx = flags[0];
    int n = blockIdx.x * 4 + (threadIdx.x >> 6);
    if (n >= N) return;
    int deg = cnt[n];
    if (deg <= CAP) return;          // hot kernel handled it
    int lane = threadIdx.x & 63;
    int g = lane >> 4;
    int gl = lane & 15;
    const int* eb = bucket + n * CAP;
    int sc = flags[2]; if (sc > SPILLCAP) sc = SPILLCAP;
    float2 adv = *(const float2*)(ad_ + 2 * n);
    float ad0 = adv.x, ad1 = adv.y;

    float m0 = -1e30f, m1 = -1e30f;
    for (int i = lane; i < CAP; i += 64) {
        int s = eb[i]; if ((unsigned)s >= (unsigned)N) s = 0;
        float2 av = *(const float2*)(as_ + 2 * s);
        m0 = fmaxf(m0, leaky(av.x + ad0));
        m1 = fmaxf(m1, leaky(av.y + ad1));
    }
    for (int i = lane; i < sc; i += 64) {
        if (spill[2 * i] == n) {
            int s = spill[2 * i + 1]; if ((unsigned)s >= (unsigned)N) s = 0;
            float2 av = *(const float2*)(as_ + 2 * s);
            m0 = fmaxf(m0, leaky(av.x + ad0));
            m1 = fmaxf(m1, leaky(av.y + ad1));
        }
    }
#pragma unroll
    for (int m = 1; m < 64; m <<= 1) { m0 = fmaxf(m0, __shfl_xor(m0, m)); m1 = fmaxf(m1, __shfl_xor(m1, m)); }

    float acc0[8] = {0,0,0,0,0,0,0,0}, acc1[8] = {0,0,0,0,0,0,0,0};
    float z0 = 0.f, z1 = 0.f;
    {
        bool act = lane < CAP;
        int s = 0; float w0 = 0.f, w1 = 0.f;
        if (act) {
            s = eb[lane]; if ((unsigned)s >= (unsigned)N) s = 0;
            float2 av = *(const float2*)(as_ + 2 * s);
            w0 = __expf(leaky(av.x + ad0) - m0);
            w1 = __expf(leaky(av.y + ad1) - m1);
            z0 += w0; z1 += w1;
        }
        for (int j = 0; 4 * j < CAP; j++) {
            int e = 4 * j + g;
            int sq    = __shfl(s, e);
            float wq0 = __shfl(w0, e);
            float wq1 = __shfl(w1, e);
            if (e < CAP) {
                const unsigned short* row = Hb + ((size_t)sq << 8);
                uint4 q0 = *(const uint4*)(row + gl * 8);
                uint4 q1 = *(const uint4*)(row + 128 + gl * 8);
                acc8(acc0, wq0, q0);
                acc8(acc1, wq1, q1);
            }
        }
    }
    for (int i = 0; i < sc; i++) {
        int d = spill[2 * i];
        if (d != n) continue;
        int s = spill[2 * i + 1]; if ((unsigned)s >= (unsigned)N) s = 0;
        float2 av = *(const float2*)(as_ + 2 * s);
        float w0 = __expf(leaky(av.x + ad0) - m0);
        float w1 = __expf(leaky(av.y + ad1) - m1);
        if (lane == 0) { z0 += w0; z1 += w1; }
        if (g == 0) {
            const unsigned short* row = Hb + ((size_t)s << 8);
            uint4 q0 = *(const uint4*)(row + gl * 8);
            uint4 q1 = *(const uint4*)(row + 128 + gl * 8);
            acc8(acc0, w0, q0);
            acc8(acc1, w1, q1);
        }
    }
#pragma unroll
    for (int m = 1; m < 64; m <<= 1) { z0 += __shfl_xor(z0, m); z1 += __shfl_xor(z1, m); }

    float inv0 = 1.f / (z0 + 1e-16f), inv1 = 1.f / (z1 + 1e-16f);
#pragma unroll
    for (int k = 0; k < 8; k++) {
        acc0[k] += __shfl_xor(acc0[k], 16); acc0[k] += __shfl_xor(acc0[k], 32);
        acc1[k] += __shfl_xor(acc1[k], 16); acc1[k] += __shfl_xor(acc1[k], 32);
    }
    float vv[8];
    if (fx) {
        const float* bf = (const float*)bias + layer * 128 + gl * 8;
#pragma unroll
        for (int k = 0; k < 8; k++) vv[k] = 0.5f * (acc0[k] * inv0 + acc1[k] * inv1) + bf[k];
    } else {
        const unsigned short* bh = (const unsigned short*)bias + layer * 128 + gl * 8;
        uint4 bv = *(const uint4*)bh;
        float bfv[8] = { bflo(bv.x), bfhi(bv.x), bflo(bv.y), bfhi(bv.y),
                         bflo(bv.z), bfhi(bv.z), bflo(bv.w), bfhi(bv.w) };
#pragma unroll
        for (int k = 0; k < 8; k++) vv[k] = 0.5f * (acc0[k] * inv0 + acc1[k] * inv1) + bfv[k];
    }
    float ss = 0.f;
#pragma unroll
    for (int k = 0; k < 8; k++) ss += vv[k] * vv[k];
#pragma unroll
    for (int m = 1; m < 16; m <<= 1) ss += __shfl_xor(ss, m);
    float inv = 1.f / fmaxf(sqrtf(ss), 1e-12f);
    if (lane < 16) {
        if (fx) {
            float* op = (float*)outp + (size_t)n * 128 + gl * 8;
            float4 o0 = { vv[0] * inv, vv[1] * inv, vv[2] * inv, vv[3] * inv };
            float4 o1 = { vv[4] * inv, vv[5] * inv, vv[6] * inv, vv[7] * inv };
            *(float4*)op = o0;
            *(float4*)(op + 4) = o1;
        } else {
            unsigned short* op = (unsigned short*)outp + (size_t)n * 128 + gl * 8;
            uint4 pk;
            pk.x = (unsigned int)f2bf(vv[0] * inv) | ((unsigned int)f2bf(vv[1] * inv) << 16);
            pk.y = (unsigned int)f2bf(vv[2] * inv) | ((unsigned int)f2bf(vv[3] * inv) << 16);
            pk.z = (unsigned int)f2bf(vv[4] * inv) | ((unsigned int)f2bf(vv[5] * inv) << 16);
            pk.w = (unsigned int)f2bf(vv[6] * inv) | ((unsigned int)f2bf(vv[7] * inv) << 16);
            *(uint4*)op = pk;
        }
    }
}

extern "C" void kernel_launch(void* const* d_in, const int* in_sizes, int n_in,
                              void* d_out, int out_size, void* d_ws, size_t ws_size,
                              hipStream_t stream) {
    const void* x    = d_in[0];
    const int*  ei   = (const int*)d_in[1];
    const void* W    = d_in[2];
    const void* atts = d_in[3];
    const void* attd = d_in[4];
    const void* bias = d_in[5];

    int N = in_sizes[0] / 128;
    int E = in_sizes[1] / 2;

    char* p = (char*)d_ws;
    auto alloc = [&](size_t bytes) -> char* {
        char* q = p; p += (bytes + 255) & ~(size_t)255; return q;
    };
    int* flags   = (int*)alloc(256);                                   // [0]=fx [1]=is64 [2]=spillcnt
    int* cnt     = (int*)alloc((size_t)N * 4);
    float* as_   = (float*)alloc((size_t)N * 2 * 4);
    float* ad_   = (float*)alloc((size_t)N * 2 * 4);
    unsigned short* wt = (unsigned short*)alloc(2 * 256 * 128 * 2);
    int* spill   = (int*)alloc((size_t)SPILLCAP * 2 * 4);              // 512 KB
    int* bucket  = (int*)alloc((size_t)N * CAP * 4);                   // 9.6 MB
    unsigned short* hbuf = (unsigned short*)alloc((size_t)N * 256 * 2);// 25.6 MB
    // total ~36.9 MB

    k_probe_zero<<<(N + 255) / 256, 256, 0, stream>>>((const unsigned int*)x, ei, flags, cnt, N);
    k_bucket<<<(E + N + 255) / 256, 256, 0, stream>>>(ei, E, N, flags, cnt, bucket, spill);
    k_transpose<<<256, 256, 0, stream>>>(W, wt, flags);

    int mtiles = (N + 15) / 16;
    int ngrp = (N + 3) / 4;
    for (int l = 0; l < 2; l++) {
        const void* xin = (l == 0) ? x : (const void*)d_out;
        k_gemm_alpha<<<mtiles, 256, 0, stream>>>(xin, wt + l * 32768, atts, attd, l,
                                                 hbuf, as_, ad_, N, flags);
        k_aggregate<<<ngrp, 256, 0, stream>>>(hbuf, as_, ad_, cnt, bucket,
                                              bias, l, flags, d_out, N);
        k_spillfix<<<ngrp, 256, 0, stream>>>(hbuf, as_, ad_, cnt, bucket, spill, flags,
                                             bias, l, d_out, N);
    }
}